// Round 2
// baseline (2540.804 us; speedup 1.0000x reference)
//
#include <hip/hip_runtime.h>
#include <hip/hip_bf16.h>

#define ROWS 230400   // 1600 windows * 144 tokens
#define CDIM 192
#define NTOK 144
#define NWIN 1600
#define PLANE 57600   // 240*240
#define HDIM 768

typedef __attribute__((ext_vector_type(8))) short bf16x8;
typedef __attribute__((ext_vector_type(4))) float f32x4;

__device__ __forceinline__ ushort f2bf(float f) {
  union { float f; unsigned u; } v; v.f = f;
  unsigned r = v.u + 0x7FFFu + ((v.u >> 16) & 1u);
  return (ushort)(r >> 16);
}
__device__ __forceinline__ float bf2f(ushort h) {
  union { unsigned u; float f; } v; v.u = ((unsigned)h) << 16;
  return v.f;
}
// tanh-approx gelu; |err| vs exact erf-gelu < ~0.003, well inside 0.11 abs threshold.
// 1 - 2/(e+1) form is overflow-safe (e=inf -> 1, e=0 -> -1).
__device__ __forceinline__ float gelu_f(float x) {
  float u = 1.5957691216057308f * (x + 0.044715f * x * x * x);  // 2*sqrt(2/pi)*(...)
  float e = __expf(u);
  float t = 1.f - 2.f / (e + 1.f);
  return 0.5f * x * (1.f + t);
}

// ---------------- weight fp32 -> bf16 ----------------
struct CvtJobs {
  const float* src[8];
  ushort* dst[8];
  int n[8];
};
__global__ __launch_bounds__(256) void cvt_kernel(CvtJobs jobs) {
  int stride = gridDim.x * blockDim.x;
  int t0 = blockIdx.x * blockDim.x + threadIdx.x;
  for (int j = 0; j < 8; ++j) {
    const float* s = jobs.src[j]; ushort* d = jobs.dst[j]; int n = jobs.n[j];
    for (int e = t0; e < n; e += stride) d[e] = f2bf(s[e]);
  }
}

// ---------------- window partition + LN (opt & sar) ----------------
#define XSTR 194  // row stride in ushorts: 97 dwords == 1 mod 32 -> conflict-free row scans
__global__ __launch_bounds__(256) void lnpart_kernel(
    const float* __restrict__ opt, const float* __restrict__ sar,
    const float* __restrict__ lnqw, const float* __restrict__ lnqb,
    const float* __restrict__ lnkw, const float* __restrict__ lnkb,
    ushort* __restrict__ opt_ln, ushort* __restrict__ sar_ln,
    ushort* __restrict__ opt_tok) {
  __shared__ __align__(16) ushort X[NTOK * XSTR];
  __shared__ float smu[NTOK], srs[NTOK];
  int win = blockIdx.x;
  int b = win / 400, rr = win % 400, nh = rr / 20, nw = rr % 20;
  size_t wbase = (size_t)b * CDIM * PLANE + (size_t)(nh * 12) * 240 + nw * 12;
  int tid = threadIdx.x;
  for (int pass = 0; pass < 2; ++pass) {
    const float* src = pass ? sar : opt;
    for (int e = tid; e < CDIM * 36; e += 256) {
      int c = e / 36, r2 = e % 36, i = r2 / 3, j0 = (r2 % 3) * 4;
      float4 v = *(const float4*)&src[wbase + (size_t)c * PLANE + i * 240 + j0];
      int tok = i * 12 + j0;
      X[(tok + 0) * XSTR + c] = f2bf(v.x);
      X[(tok + 1) * XSTR + c] = f2bf(v.y);
      X[(tok + 2) * XSTR + c] = f2bf(v.z);
      X[(tok + 3) * XSTR + c] = f2bf(v.w);
    }
    __syncthreads();
    if (tid < NTOK) {
      const uint* row = (const uint*)&X[tid * XSTR];  // 4B-aligned (194*2=388)
      float s = 0.f, qs = 0.f;
      for (int i = 0; i < 96; ++i) {
        uint u = row[i];
        float a = bf2f((ushort)(u & 0xffffu)), bb2 = bf2f((ushort)(u >> 16));
        s += a + bb2; qs += a * a + bb2 * bb2;
      }
      float mu = s * (1.f / CDIM);
      smu[tid] = mu;
      srs[tid] = rsqrtf(qs * (1.f / CDIM) - mu * mu + 1e-5f);
    }
    __syncthreads();
    const float* w = pass ? lnkw : lnqw;
    const float* bb = pass ? lnkb : lnqb;
    ushort* dst = pass ? sar_ln : opt_ln;
    for (int e = tid; e < NTOK * CDIM; e += 256) {
      int tok = e / CDIM, c = e % CDIM;
      ushort raw = X[tok * XSTR + c];
      float v = bf2f(raw);
      float y = (v - smu[tok]) * srs[tok] * w[c] + bb[c];
      size_t o = (size_t)(win * NTOK + tok) * CDIM + c;
      dst[o] = f2bf(y);
      if (!pass) opt_tok[o] = raw;
    }
    __syncthreads();
  }
}

// ---------------- merged QKV GEMM ----------------
// y<3: q = opt_ln @ wq^T + bq  (N=192, cols y*64..)
// y>=3: kv = sar_ln @ wkv^T + [bk|bv] (N=384, cols (y-3)*64..)
__global__ __launch_bounds__(256, 3) void qkv_kernel(
    const ushort* __restrict__ opt_ln, const ushort* __restrict__ sar_ln,
    const ushort* __restrict__ wq_bf, const ushort* __restrict__ wkv_bf,
    const float* __restrict__ bq, const float* __restrict__ bk,
    const float* __restrict__ bv,
    ushort* __restrict__ qb, ushort* __restrict__ kvb) {
  __shared__ __align__(16) ushort Alds[128 * 200];
  int y = blockIdx.y;
  const ushort* A; const ushort* Wt; ushort* out; int N, n0;
  if (y < 3) { A = opt_ln; Wt = wq_bf;  out = qb;  N = 192; n0 = y * 64; }
  else       { A = sar_ln; Wt = wkv_bf; out = kvb; N = 384; n0 = (y - 3) * 64; }
  int m0 = blockIdx.x * 128;
  int tid = threadIdx.x, wave = tid >> 6, lane = tid & 63, ls = lane & 15, quad = lane >> 4;
  for (int it = 0; it < 12; ++it) {
    int ch = tid + 256 * it;
    int r = ch / 24, c8 = (ch % 24) * 8;
    *(bf16x8*)&Alds[r * 200 + c8] = *(const bf16x8*)&A[(size_t)(m0 + r) * CDIM + c8];
  }
  __syncthreads();
  int mb = wave * 32;
  f32x4 acc[2][4] = {};
  for (int k0 = 0; k0 < CDIM; k0 += 32) {
    bf16x8 af0 = *(const bf16x8*)&Alds[(mb + ls) * 200 + k0 + quad * 8];
    bf16x8 af1 = *(const bf16x8*)&Alds[(mb + 16 + ls) * 200 + k0 + quad * 8];
    for (int nf = 0; nf < 4; ++nf) {
      bf16x8 bw = *(const bf16x8*)&Wt[(size_t)(n0 + nf * 16 + ls) * CDIM + k0 + quad * 8];
      acc[0][nf] = __builtin_amdgcn_mfma_f32_16x16x32_bf16(af0, bw, acc[0][nf], 0, 0, 0);
      acc[1][nf] = __builtin_amdgcn_mfma_f32_16x16x32_bf16(af1, bw, acc[1][nf], 0, 0, 0);
    }
  }
  for (int s = 0; s < 2; ++s) {
    int rowbase = m0 + mb + s * 16 + quad * 4;
    for (int nf = 0; nf < 4; ++nf) {
      int col = n0 + nf * 16 + ls;
      float bb = (y < 3) ? bq[col] : ((col < 192) ? bk[col] : bv[col - 192]);
      for (int r = 0; r < 4; ++r)
        out[(size_t)(rowbase + r) * N + col] = f2bf(acc[s][nf][r] + bb);
    }
  }
}

// ---------------- small GEMM for gate path (kept from R1) ----------------
enum { EPI_GELU = 1, EPI_SIG = 2 };
template <int EPI>
__global__ __launch_bounds__(256) void gemm_kernel(
    const ushort* __restrict__ A, const ushort* __restrict__ Wt,
    const float* __restrict__ bias, void* __restrict__ outp, int M, int N, int K) {
  __shared__ __align__(16) ushort Alds[128 * 40];
  int m0 = blockIdx.x * 128;
  int n0 = blockIdx.y * 64;
  int tid = threadIdx.x;
  int wave = tid >> 6, lane = tid & 63, ls = lane & 15, quad = lane >> 4;
  f32x4 acc[2][4] = {};
  for (int k0 = 0; k0 < K; k0 += 32) {
    for (int it = 0; it < 2; ++it) {
      int ch = tid + 256 * it;
      int r = ch >> 2, c8 = (ch & 3) * 8;
      int grow = m0 + r; if (grow > M - 1) grow = M - 1;
      *(bf16x8*)&Alds[r * 40 + c8] = *(const bf16x8*)&A[(size_t)grow * K + k0 + c8];
    }
    __syncthreads();
    int mb = wave * 32;
    bf16x8 af0 = *(const bf16x8*)&Alds[(mb + ls) * 40 + quad * 8];
    bf16x8 af1 = *(const bf16x8*)&Alds[(mb + 16 + ls) * 40 + quad * 8];
    for (int nf = 0; nf < 4; ++nf) {
      bf16x8 bw = *(const bf16x8*)&Wt[(size_t)(n0 + nf * 16 + ls) * K + k0 + quad * 8];
      acc[0][nf] = __builtin_amdgcn_mfma_f32_16x16x32_bf16(af0, bw, acc[0][nf], 0, 0, 0);
      acc[1][nf] = __builtin_amdgcn_mfma_f32_16x16x32_bf16(af1, bw, acc[1][nf], 0, 0, 0);
    }
    __syncthreads();
  }
  for (int s = 0; s < 2; ++s) {
    int rowbase = m0 + wave * 32 + s * 16 + quad * 4;
    for (int nf = 0; nf < 4; ++nf) {
      int col = n0 + nf * 16 + ls;
      float bb = bias[col];
      for (int r = 0; r < 4; ++r) {
        int row = rowbase + r;
        if (row >= M) continue;
        float v = acc[s][nf][r] + bb;
        if (EPI == EPI_GELU) ((ushort*)outp)[(size_t)row * N + col] = f2bf(gelu_f(v));
        else ((float*)outp)[(size_t)row * N + col] = 1.f / (1.f + __expf(-v));
      }
    }
  }
}

// ---------------- per-window token-mean of sar_ln ----------------
__global__ __launch_bounds__(192) void pool_kernel(const ushort* __restrict__ sar_ln,
                                                   ushort* __restrict__ pool) {
  int win = blockIdx.x, c = threadIdx.x;
  float s = 0.f;
  size_t base = (size_t)win * NTOK * CDIM + c;
  for (int t = 0; t < NTOK; ++t) s += bf2f(sar_ln[base + (size_t)t * CDIM]);
  pool[(size_t)win * CDIM + c] = f2bf(s * (1.f / NTOK));
}

// ---------------- attention: one block per (window, head) ----------------
__global__ __launch_bounds__(256) void attn_kernel(const ushort* __restrict__ q,
                                                   const ushort* __restrict__ kv,
                                                   ushort* __restrict__ attn_out) {
  __shared__ __align__(16) ushort vT[32 * 168];     // v transposed, K zero-padded to 160
  __shared__ __align__(16) ushort P[4][16 * 168];   // per-wave P tile (A-layout source)
  int blk = blockIdx.x;
  int win = blk / 6, head = blk % 6;
  int tid = threadIdx.x, wave = tid >> 6, lane = tid & 63, ls = lane & 15, quad = lane >> 4;
  size_t qbase = (size_t)win * NTOK * CDIM + head * 32;
  size_t kbase = (size_t)win * NTOK * 384 + head * 32;
  size_t vbase = kbase + 192;
  for (int e = tid; e < NTOK * 32; e += 256) {
    int t = e >> 5, d = e & 31;
    vT[d * 168 + t] = kv[vbase + (size_t)t * 384 + d];
  }
  for (int e = tid; e < 32 * 24; e += 256) {
    int d = e / 24, j = 144 + e % 24;
    vT[d * 168 + j] = 0;
  }
  ushort* Pw = P[wave];
  for (int e = lane; e < 16 * 24; e += 64) {  // zero K-pad cols 144..167 once
    int r = e / 24, j = 144 + e % 24;
    Pw[r * 168 + j] = 0;
  }
  __syncthreads();
  const float scale = 0.17677669529663687f;  // 32^-0.5
  f32x4 zero = {0.f, 0.f, 0.f, 0.f};
  for (int mt = wave; mt < 9; mt += 4) {
    int m0 = mt * 16;
    bf16x8 aq = *(const bf16x8*)&q[qbase + (size_t)(m0 + ls) * CDIM + quad * 8];
    f32x4 S[9];
    for (int nt = 0; nt < 9; ++nt) {
      bf16x8 bk = *(const bf16x8*)&kv[kbase + (size_t)(nt * 16 + ls) * 384 + quad * 8];
      S[nt] = __builtin_amdgcn_mfma_f32_16x16x32_bf16(aq, bk, zero, 0, 0, 0);
    }
    for (int nt = 0; nt < 9; ++nt)
      for (int r = 0; r < 4; ++r) S[nt][r] *= scale;
    for (int r = 0; r < 4; ++r) {
      float mx = -1e30f;
      for (int nt = 0; nt < 9; ++nt) mx = fmaxf(mx, S[nt][r]);
      for (int o = 1; o < 16; o <<= 1) mx = fmaxf(mx, __shfl_xor(mx, o));
      float sm = 0.f;
      for (int nt = 0; nt < 9; ++nt) { float e = __expf(S[nt][r] - mx); S[nt][r] = e; sm += e; }
      for (int o = 1; o < 16; o <<= 1) sm += __shfl_xor(sm, o);
      float inv = 1.f / sm;
      for (int nt = 0; nt < 9; ++nt)
        Pw[(quad * 4 + r) * 168 + nt * 16 + ls] = f2bf(S[nt][r] * inv);
    }
    f32x4 O[2] = {};
    for (int ks = 0; ks < 5; ++ks) {
      bf16x8 ap = *(const bf16x8*)&Pw[ls * 168 + ks * 32 + quad * 8];
      for (int dt = 0; dt < 2; ++dt) {
        bf16x8 bv = *(const bf16x8*)&vT[(dt * 16 + ls) * 168 + ks * 32 + quad * 8];
        O[dt] = __builtin_amdgcn_mfma_f32_16x16x32_bf16(ap, bv, O[dt], 0, 0, 0);
      }
    }
    for (int dt = 0; dt < 2; ++dt)
      for (int r = 0; r < 4; ++r)
        attn_out[(size_t)(win * NTOK + m0 + quad * 4 + r) * CDIM + head * 32 + dt * 16 + ls] =
            f2bf(O[dt][r]);
  }
}

// ---------------- proj GEMM + gate + residual + output LN, fused ----------------
// fused = opt_tok + gamma * g * (attn_out @ wp^T + bp);  h = LN(fused)
__global__ __launch_bounds__(256, 2) void projln_kernel(
    const ushort* __restrict__ A, const ushort* __restrict__ wp_bf,
    const float* __restrict__ bp, const float* __restrict__ g,
    const ushort* __restrict__ opt_tok, const float* __restrict__ gamma_p,
    const float* __restrict__ lnow, const float* __restrict__ lnob,
    ushort* __restrict__ fused, ushort* __restrict__ h) {
  __shared__ __align__(16) ushort Alds[128 * 200];
  int m0 = blockIdx.x * 128;
  int tid = threadIdx.x, wave = tid >> 6, lane = tid & 63, ls = lane & 15, quad = lane >> 4;
  for (int it = 0; it < 12; ++it) {
    int ch = tid + 256 * it;
    int r = ch / 24, c8 = (ch % 24) * 8;
    *(bf16x8*)&Alds[r * 200 + c8] = *(const bf16x8*)&A[(size_t)(m0 + r) * CDIM + c8];
  }
  __syncthreads();
  int mb = wave * 32;
  f32x4 acc[2][12] = {};
  for (int k0 = 0; k0 < CDIM; k0 += 32) {
    bf16x8 af0 = *(const bf16x8*)&Alds[(mb + ls) * 200 + k0 + quad * 8];
    bf16x8 af1 = *(const bf16x8*)&Alds[(mb + 16 + ls) * 200 + k0 + quad * 8];
    for (int nf = 0; nf < 12; ++nf) {
      bf16x8 bw = *(const bf16x8*)&wp_bf[(size_t)(nf * 16 + ls) * CDIM + k0 + quad * 8];
      acc[0][nf] = __builtin_amdgcn_mfma_f32_16x16x32_bf16(af0, bw, acc[0][nf], 0, 0, 0);
      acc[1][nf] = __builtin_amdgcn_mfma_f32_16x16x32_bf16(af1, bw, acc[1][nf], 0, 0, 0);
    }
  }
  float gam = gamma_p[0];
  for (int s = 0; s < 2; ++s) {
    for (int r = 0; r < 4; ++r) {
      int rg = m0 + mb + s * 16 + quad * 4 + r;
      int win = rg / NTOK;
      float fv[12], s1 = 0.f, s2 = 0.f;
      for (int nf = 0; nf < 12; ++nf) {
        int col = nf * 16 + ls;
        float v = acc[s][nf][r] + bp[col];
        float f = bf2f(opt_tok[(size_t)rg * CDIM + col]) + gam * g[(size_t)win * CDIM + col] * v;
        fv[nf] = f; s1 += f; s2 += f * f;
      }
      for (int o = 1; o < 16; o <<= 1) { s1 += __shfl_xor(s1, o); s2 += __shfl_xor(s2, o); }
      float mu = s1 * (1.f / CDIM);
      float rs = rsqrtf(s2 * (1.f / CDIM) - mu * mu + 1e-5f);
      for (int nf = 0; nf < 12; ++nf) {
        int col = nf * 16 + ls;
        size_t idx = (size_t)rg * CDIM + col;
        fused[idx] = f2bf(fv[nf]);
        h[idx] = f2bf((fv[nf] - mu) * rs * lnow[col] + lnob[col]);
      }
    }
  }
}

// ---------------- fused MLP v2: y = fused + gelu(h@w1^T+b1)@w2^T + b2 ----------------
// 64-row blocks, 16 rows/wave, wave-private Ts -> no barriers in hc loop.
__global__ __launch_bounds__(256, 3) void mlp_kernel(
    const ushort* __restrict__ h, const ushort* __restrict__ fused,
    const ushort* __restrict__ w1b, const float* __restrict__ b1,
    const ushort* __restrict__ w2b, const float* __restrict__ b2,
    ushort* __restrict__ y) {
  __shared__ __align__(16) ushort Hs[64 * 200];
  __shared__ __align__(16) ushort Ts[4][16 * 72];
  int m0 = blockIdx.x * 64;
  int tid = threadIdx.x, wave = tid >> 6, lane = tid & 63, ls = lane & 15, quad = lane >> 4;
  for (int it = 0; it < 6; ++it) {
    int ch = tid + 256 * it;
    int r = ch / 24, c8 = (ch % 24) * 8;
    *(bf16x8*)&Hs[r * 200 + c8] = *(const bf16x8*)&h[(size_t)(m0 + r) * CDIM + c8];
  }
  __syncthreads();
  int mb = wave * 16;
  ushort* Tw = Ts[wave];
  f32x4 acc[12] = {};
#pragma unroll 1
  for (int hc = 0; hc < HDIM; hc += 64) {
    f32x4 t[4] = {};
    for (int ks = 0; ks < 6; ++ks) {
      bf16x8 a = *(const bf16x8*)&Hs[(mb + ls) * 200 + ks * 32 + quad * 8];
      for (int nf = 0; nf < 4; ++nf) {
        bf16x8 bw = *(const bf16x8*)&w1b[(size_t)(hc + nf * 16 + ls) * CDIM + ks * 32 + quad * 8];
        t[nf] = __builtin_amdgcn_mfma_f32_16x16x32_bf16(a, bw, t[nf], 0, 0, 0);
      }
    }
    for (int nf = 0; nf < 4; ++nf) {
      float bb = b1[hc + nf * 16 + ls];
      for (int r = 0; r < 4; ++r)
        Tw[(quad * 4 + r) * 72 + nf * 16 + ls] = f2bf(gelu_f(t[nf][r] + bb));
    }
    for (int ks = 0; ks < 2; ++ks) {
      bf16x8 ap = *(const bf16x8*)&Tw[ls * 72 + ks * 32 + quad * 8];
      for (int nf = 0; nf < 12; ++nf) {
        bf16x8 bw = *(const bf16x8*)&w2b[(size_t)(nf * 16 + ls) * HDIM + hc + ks * 32 + quad * 8];
        acc[nf] = __builtin_amdgcn_mfma_f32_16x16x32_bf16(ap, bw, acc[nf], 0, 0, 0);
      }
    }
  }
  for (int nf = 0; nf < 12; ++nf) {
    float bb = b2[nf * 16 + ls];
    for (int r = 0; r < 4; ++r) {
      size_t idx = (size_t)(m0 + mb + quad * 4 + r) * CDIM + nf * 16 + ls;
      y[idx] = f2bf(bf2f(fused[idx]) + acc[nf][r] + bb);
    }
  }
}

// ---------------- window reverse -> [B,C,H,W] fp32 ----------------
__global__ __launch_bounds__(256) void unpart_kernel(const ushort* __restrict__ y,
                                                     float* __restrict__ out) {
  __shared__ __align__(16) ushort X[NTOK * 200];
  int win = blockIdx.x;
  int b = win / 400, rr = win % 400, nh = rr / 20, nw = rr % 20;
  size_t wbase = (size_t)b * CDIM * PLANE + (size_t)(nh * 12) * 240 + nw * 12;
  int tid = threadIdx.x;
  for (int e = tid; e < NTOK * 24; e += 256) {
    int tok = e / 24, c8 = (e % 24) * 8;
    *(bf16x8*)&X[tok * 200 + c8] = *(const bf16x8*)&y[(size_t)(win * NTOK + tok) * CDIM + c8];
  }
  __syncthreads();
  for (int e = tid; e < CDIM * 36; e += 256) {
    int c = e / 36, r2 = e % 36, i = r2 / 3, j0 = (r2 % 3) * 4;
    int tok = i * 12 + j0;
    float4 v;
    v.x = bf2f(X[(tok + 0) * 200 + c]);
    v.y = bf2f(X[(tok + 1) * 200 + c]);
    v.z = bf2f(X[(tok + 2) * 200 + c]);
    v.w = bf2f(X[(tok + 3) * 200 + c]);
    *(float4*)&out[wbase + (size_t)c * PLANE + i * 240 + j0] = v;
  }
}

extern "C" void kernel_launch(void* const* d_in, const int* in_sizes, int n_in,
                              void* d_out, int out_size, void* d_ws, size_t ws_size,
                              hipStream_t stream) {
  const float* opt   = (const float*)d_in[0];
  const float* sar   = (const float*)d_in[1];
  const float* lnqw  = (const float*)d_in[2];
  const float* lnqb  = (const float*)d_in[3];
  const float* lnkw  = (const float*)d_in[4];
  const float* lnkb  = (const float*)d_in[5];
  const float* wq    = (const float*)d_in[6];
  const float* bq    = (const float*)d_in[7];
  const float* wk    = (const float*)d_in[8];
  const float* bk    = (const float*)d_in[9];
  const float* wv    = (const float*)d_in[10];
  const float* bv    = (const float*)d_in[11];
  const float* wp    = (const float*)d_in[12];
  const float* bp    = (const float*)d_in[13];
  const float* gw1   = (const float*)d_in[14];
  const float* gb1   = (const float*)d_in[15];
  const float* gw2   = (const float*)d_in[16];
  const float* gb2   = (const float*)d_in[17];
  const float* gamma = (const float*)d_in[18];
  const float* lnow  = (const float*)d_in[19];
  const float* lnob  = (const float*)d_in[20];
  const float* w1    = (const float*)d_in[21];
  const float* b1    = (const float*)d_in[22];
  const float* w2    = (const float*)d_in[23];
  const float* b2    = (const float*)d_in[24];

  char* ws = (char*)d_ws;
  size_t off = 0;
  auto take = [&](size_t bytes) -> char* {
    char* p = ws + off;
    off += (bytes + 255) & ~(size_t)255;
    return p;
  };
  const size_t big = (size_t)ROWS * CDIM * 2;  // 88.5 MB
  ushort* opt_ln  = (ushort*)take(big);                 // -> reused as h
  ushort* sar_ln  = (ushort*)take(big);                 // -> attn_out -> y
  ushort* opt_tok = (ushort*)take(big);
  ushort* qb      = (ushort*)take(big);                 // -> fused
  ushort* kv      = (ushort*)take((size_t)ROWS * 384 * 2);
  ushort* wq_bf   = (ushort*)take(CDIM * CDIM * 2);
  ushort* wkv_bf  = (ushort*)take(2 * CDIM * CDIM * 2);
  ushort* wp_bf   = (ushort*)take(CDIM * CDIM * 2);
  ushort* w1_bf   = (ushort*)take((size_t)HDIM * CDIM * 2);
  ushort* w2_bf   = (ushort*)take((size_t)CDIM * HDIM * 2);
  ushort* gw1_bf  = (ushort*)take(CDIM * CDIM * 2);
  ushort* gw2_bf  = (ushort*)take(CDIM * CDIM * 2);
  ushort* pool_bf = (ushort*)take(NWIN * CDIM * 2);
  ushort* g1_bf   = (ushort*)take(NWIN * CDIM * 2);
  float*  g_f     = (float*)take(NWIN * CDIM * 4);
  ushort* h        = opt_ln;
  ushort* attn_out = sar_ln;
  ushort* fused    = qb;
  ushort* yb       = sar_ln;

  CvtJobs jobs;
  jobs.src[0] = wq;  jobs.dst[0] = wq_bf;               jobs.n[0] = CDIM * CDIM;
  jobs.src[1] = wk;  jobs.dst[1] = wkv_bf;              jobs.n[1] = CDIM * CDIM;
  jobs.src[2] = wv;  jobs.dst[2] = wkv_bf + CDIM * CDIM; jobs.n[2] = CDIM * CDIM;
  jobs.src[3] = wp;  jobs.dst[3] = wp_bf;               jobs.n[3] = CDIM * CDIM;
  jobs.src[4] = w1;  jobs.dst[4] = w1_bf;               jobs.n[4] = HDIM * CDIM;
  jobs.src[5] = w2;  jobs.dst[5] = w2_bf;               jobs.n[5] = CDIM * HDIM;
  jobs.src[6] = gw1; jobs.dst[6] = gw1_bf;              jobs.n[6] = CDIM * CDIM;
  jobs.src[7] = gw2; jobs.dst[7] = gw2_bf;              jobs.n[7] = CDIM * CDIM;
  cvt_kernel<<<dim3(128), dim3(256), 0, stream>>>(jobs);

  lnpart_kernel<<<dim3(NWIN), dim3(256), 0, stream>>>(
      opt, sar, lnqw, lnqb, lnkw, lnkb, opt_ln, sar_ln, opt_tok);

  qkv_kernel<<<dim3(1800, 9), dim3(256), 0, stream>>>(
      opt_ln, sar_ln, wq_bf, wkv_bf, bq, bk, bv, qb, kv);

  pool_kernel<<<dim3(NWIN), dim3(192), 0, stream>>>(sar_ln, pool_bf);
  gemm_kernel<EPI_GELU><<<dim3(13, 3), dim3(256), 0, stream>>>(
      pool_bf, gw1_bf, gb1, (void*)g1_bf, NWIN, CDIM, CDIM);
  gemm_kernel<EPI_SIG><<<dim3(13, 3), dim3(256), 0, stream>>>(
      g1_bf, gw2_bf, gb2, (void*)g_f, NWIN, CDIM, CDIM);

  attn_kernel<<<dim3(NWIN * 6), dim3(256), 0, stream>>>(qb, kv, attn_out);

  projln_kernel<<<dim3(1800), dim3(256), 0, stream>>>(
      attn_out, wp_bf, bp, g_f, opt_tok, gamma, lnow, lnob, fused, h);

  mlp_kernel<<<dim3(3600), dim3(256), 0, stream>>>(h, fused, w1_bf, b1, w2_bf, b2, yb);

  unpart_kernel<<<dim3(NWIN), dim3(256), 0, stream>>>(yb, (float*)d_out);
}